// Round 10
// baseline (1065.800 us; speedup 1.0000x reference)
//
#include <hip/hip_runtime.h>

// WaveConv1d on MI355X — round 21: einsum_v13b (fix OOB double-count of i0).
//   out = x + idwt(E1(lo4)-lo4, E2(h4)-h4, 0, 0, 0)
// r20 post-mortem: v13 crashed — ISSUE was called with CI = i0+ch while
// xb0/wb0 already include i0 => addresses double-counted i0, OOB page fault
// for iq>0. Theory untested. v13b: identical kernel, chunk-RELATIVE indices
// (prologue 0,1; steady state CH+2). Everything else unchanged:
// block owns FULL k for an o-pair (w reads = 4KB page-sequential per i, each
// w byte read once by one block); w global->reg; x via global_load_lds into
// wave-private LDS slabs => ZERO barriers; counted vmcnt(15) 2-deep pipeline;
// k-tail [512,522) in-line on lanes 0-4; i-split x4 via atomicAdd (dlo/dh
// zeroed in dwt_fused3); bid%8=(e,iq) pins x-slice sharers to one XCD.

#define NROWS 4096          // B*C
#define MODES 522

#define M1 4101
#define M2 2056
#define M3 1033
#define M4 522

typedef unsigned int  uint;
typedef unsigned short ushort;

__constant__ float c_dlo[12] = {
  -0.00107730108499558f,  0.004777257511010651f,  0.0005538422009938016f,
  -0.031582039318031156f, 0.02752286553001629f,   0.09750160558707936f,
  -0.12976686756709563f,  -0.22626469396516913f,  0.3152503517092432f,
   0.7511339080215775f,   0.4946238903983854f,    0.11154074335008017f };
__constant__ float c_dhi[12] = {
  -0.11154074335008017f,  0.4946238903983854f,   -0.7511339080215775f,
   0.3152503517092432f,   0.22626469396516913f,  -0.12976686756709563f,
  -0.09750160558707936f,  0.02752286553001629f,   0.031582039318031156f,
   0.0005538422009938016f,-0.004777257511010651f, -0.00107730108499558f };
// Analysis (time-reversed) filters
__constant__ float c_alo[12] = {
   0.11154074335008017f,  0.4946238903983854f,    0.7511339080215775f,
   0.3152503517092432f,  -0.22626469396516913f,  -0.12976686756709563f,
   0.09750160558707936f,  0.02752286553001629f,  -0.031582039318031156f,
   0.0005538422009938016f, 0.004777257511010651f, -0.00107730108499558f };
__constant__ float c_ahi[12] = {
  -0.00107730108499558f, -0.004777257511010651f,  0.0005538422009938016f,
   0.031582039318031156f, 0.02752286553001629f,  -0.09750160558707936f,
  -0.12976686756709563f,  0.22626469396516913f,   0.3152503517092432f,
  -0.7511339080215775f,   0.4946238903983854f,   -0.11154074335008017f };

__device__ __forceinline__ ushort f2bf(float f) {
    uint b = __float_as_uint(f);
    uint r = (b + 0x7fffu + ((b >> 16) & 1u)) >> 16;
    return (ushort)r;
}

__device__ __forceinline__ void gl16(const void* g, void* l) {
    __builtin_amdgcn_global_load_lds(
        (const __attribute__((address_space(1))) void*)g,
        (__attribute__((address_space(3))) void*)l, 16, 0, 0);
}

// One lo-only analysis level LDS->LDS, PAIR-vectorized.
__device__ __forceinline__
void dwt_lo_pairs(const float* __restrict__ src, int n, int m,
                  float* __restrict__ dst, int tid)
{
    int jhi = (n - 2) >> 1;
    int npairs = (m + 1) >> 1;
    for (int jp = tid; jp < npairs; jp += 256) {
        int j0 = 2 * jp;
        if (j0 >= 6 && j0 + 1 <= jhi) {
            const float2* s2 = (const float2*)(src + 2 * j0 - 10);
            float2 p0 = s2[0], p1 = s2[1], p2 = s2[2], p3 = s2[3],
                   p4 = s2[4], p5 = s2[5], p6 = s2[6];
            float a0 =
                p0.x*c_alo[0] + p0.y*c_alo[1] + p1.x*c_alo[2] + p1.y*c_alo[3] +
                p2.x*c_alo[4] + p2.y*c_alo[5] + p3.x*c_alo[6] + p3.y*c_alo[7] +
                p4.x*c_alo[8] + p4.y*c_alo[9] + p5.x*c_alo[10]+ p5.y*c_alo[11];
            float a1 =
                p1.x*c_alo[0] + p1.y*c_alo[1] + p2.x*c_alo[2] + p2.y*c_alo[3] +
                p3.x*c_alo[4] + p3.y*c_alo[5] + p4.x*c_alo[6] + p4.y*c_alo[7] +
                p5.x*c_alo[8] + p5.y*c_alo[9] + p6.x*c_alo[10]+ p6.y*c_alo[11];
            *(float2*)&dst[j0] = make_float2(a0, a1);
        } else {
#pragma unroll
            for (int q = 0; q < 2; ++q) {
                int j = j0 + q;
                if (j < m) {
                    int base = 2 * j - 10;
                    float a = 0.f;
#pragma unroll
                    for (int t = 0; t < 12; ++t) {
                        int u = base + t;
                        u = (u < 0) ? (-1 - u) : u;
                        u = (u >= n) ? (2 * n - 1 - u) : u;
                        a += src[u] * c_alo[t];
                    }
                    dst[j] = a;
                }
            }
        }
    }
}

// Fused forward DWT, lo-chain only: x -> (lo4, h4) fp32 + bf16 xT
// [c][g4][k][b4]. ALSO zero-fills dlo/dh (2*SZ contiguous) for v13's atomics.
__global__ __launch_bounds__(256)
void dwt_fused3(const float* __restrict__ x,
                float* __restrict__ lo4g, float* __restrict__ h4g,
                ushort* __restrict__ xlT, ushort* __restrict__ xhT,
                float* __restrict__ dzero)
{
    __shared__ float X[8192];
    __shared__ float LA[4104];
    int row = blockIdx.x, tid = threadIdx.x;

    // zero dlo+dh: 2*SZ floats = 1,069,056 float4s over 4096 blocks
    {
        const size_t nz = ((size_t)2 * NROWS * M4) / 4;
        float4* zp = (float4*)dzero;
        float4 z4 = make_float4(0.f, 0.f, 0.f, 0.f);
        for (size_t i = (size_t)row * 256 + tid; i < nz; i += (size_t)NROWS * 256)
            zp[i] = z4;
    }

    const float4* xr = (const float4*)(x + (size_t)row * 8192);
    float4* Xv = (float4*)X;
#pragma unroll
    for (int i = 0; i < 8; ++i) Xv[tid + 256 * i] = xr[tid + 256 * i];
    __syncthreads();

    dwt_lo_pairs(X,  8192, M1, LA, tid);
    __syncthreads();
    dwt_lo_pairs(LA, M1,   M2, X,  tid);
    __syncthreads();
    dwt_lo_pairs(X,  M2,   M3, LA, tid);
    __syncthreads();

    float* lo4r = lo4g + (size_t)row * M4;
    float* h4r  = h4g  + (size_t)row * M4;
    int b  = row >> 8, c = row & 255;
    int cg = c * 4 + (b >> 2);
    int b4 = b & 3;
    int jhi = (M3 - 2) >> 1;            // 515
    for (int jp = tid; jp < 261; jp += 256) {
        int j0 = 2 * jp;
        float alo0, ahi0, alo1, ahi1;
        if (j0 >= 6 && j0 + 1 <= jhi) {
            const float2* s2 = (const float2*)(LA + 2 * j0 - 10);
            float2 p0 = s2[0], p1 = s2[1], p2 = s2[2], p3 = s2[3],
                   p4 = s2[4], p5 = s2[5], p6 = s2[6];
            alo0 =
                p0.x*c_alo[0] + p0.y*c_alo[1] + p1.x*c_alo[2] + p1.y*c_alo[3] +
                p2.x*c_alo[4] + p2.y*c_alo[5] + p3.x*c_alo[6] + p3.y*c_alo[7] +
                p4.x*c_alo[8] + p4.y*c_alo[9] + p5.x*c_alo[10]+ p5.y*c_alo[11];
            ahi0 =
                p0.x*c_ahi[0] + p0.y*c_ahi[1] + p1.x*c_ahi[2] + p1.y*c_ahi[3] +
                p2.x*c_ahi[4] + p2.y*c_ahi[5] + p3.x*c_ahi[6] + p3.y*c_ahi[7] +
                p4.x*c_ahi[8] + p4.y*c_ahi[9] + p5.x*c_ahi[10]+ p5.y*c_ahi[11];
            alo1 =
                p1.x*c_alo[0] + p1.y*c_alo[1] + p2.x*c_alo[2] + p2.y*c_alo[3] +
                p3.x*c_alo[4] + p3.y*c_alo[5] + p4.x*c_alo[6] + p4.y*c_alo[7] +
                p5.x*c_alo[8] + p5.y*c_alo[9] + p6.x*c_alo[10]+ p6.y*c_alo[11];
            ahi1 =
                p1.x*c_ahi[0] + p1.y*c_ahi[1] + p2.x*c_ahi[2] + p2.y*c_ahi[3] +
                p3.x*c_ahi[4] + p3.y*c_ahi[5] + p4.x*c_ahi[6] + p4.y*c_ahi[7] +
                p5.x*c_ahi[8] + p5.y*c_ahi[9] + p6.x*c_ahi[10]+ p6.y*c_ahi[11];
        } else {
#pragma unroll
            for (int q = 0; q < 2; ++q) {
                int base = 2 * (j0 + q) - 10;
                float al = 0.f, ah = 0.f;
#pragma unroll
                for (int t = 0; t < 12; ++t) {
                    int u = base + t;
                    u = (u < 0) ? (-1 - u) : u;
                    u = (u >= M3) ? (2 * M3 - 1 - u) : u;
                    float v = LA[u];
                    al += v * c_alo[t]; ah += v * c_ahi[t];
                }
                if (q == 0) { alo0 = al; ahi0 = ah; }
                else        { alo1 = al; ahi1 = ah; }
            }
        }
        *(float2*)&lo4r[j0] = make_float2(alo0, alo1);
        *(float2*)&h4r[j0]  = make_float2(ahi0, ahi1);
        size_t xi = ((size_t)cg * MODES + j0) * 4 + b4;
        xlT[xi]     = f2bf(alo0);
        xlT[xi + 4] = f2bf(alo1);
        xhT[xi]     = f2bf(ahi0);
        xhT[xi + 4] = f2bf(ahi1);
    }
}

// One synthesis (lo-only) level LDS->LDS, pair-vectorized.
__device__ __forceinline__
void ilvl_lo(const float* __restrict__ S, float* __restrict__ D,
             int L, int tid)
{
    int npairs = (L + 1) >> 1;
    for (int tp = tid; tp < npairs; tp += 256) {
        int jj = 2 * tp;
        const float2* s2 = (const float2*)(S + jj);
        float2 q0 = s2[0], q1 = s2[1], q2 = s2[2];
        float e0 = q0.x*c_dlo[1] + q0.y*c_dlo[3] + q1.x*c_dlo[5]
                 + q1.y*c_dlo[7] + q2.x*c_dlo[9] + q2.y*c_dlo[11];
        float od0= q0.x*c_dlo[0] + q0.y*c_dlo[2] + q1.x*c_dlo[4]
                 + q1.y*c_dlo[6] + q2.x*c_dlo[8] + q2.y*c_dlo[10];
        if (jj + 1 < L) {
            float2 q3 = s2[3];
            float e1 = q0.y*c_dlo[1] + q1.x*c_dlo[3] + q1.y*c_dlo[5]
                     + q2.x*c_dlo[7] + q2.y*c_dlo[9] + q3.x*c_dlo[11];
            float od1= q0.y*c_dlo[0] + q1.x*c_dlo[2] + q1.y*c_dlo[4]
                     + q2.x*c_dlo[6] + q2.y*c_dlo[8] + q3.x*c_dlo[10];
            *(float4*)&D[2*jj] = make_float4(e0, od0, e1, od1);
        } else {
            D[2*jj] = e0; D[2*jj+1] = od0;
        }
    }
}

// Delta-IDWT: A = dlo-lo4, Hs = dh-h4; lvl4 full -> lvl3,2,1 lo-only -> +x.
__global__ __launch_bounds__(256)
void idwt_delta3(const float* __restrict__ dlo, const float* __restrict__ dh,
                 const float* __restrict__ lo4, const float* __restrict__ h4,
                 const float* __restrict__ x,   float* __restrict__ out)
{
    __shared__ float A[2056];
    __shared__ float B[4104];
    __shared__ float Hs[528];
    int row = blockIdx.x, tid = threadIdx.x;

    {
        const float2* dl2 = (const float2*)(dlo + (size_t)row * M4);
        const float2* lo2 = (const float2*)(lo4 + (size_t)row * M4);
        const float2* dh2 = (const float2*)(dh  + (size_t)row * M4);
        const float2* h42 = (const float2*)(h4  + (size_t)row * M4);
        for (int tp = tid; tp < 261; tp += 256) {
            float2 a = dl2[tp], bvl = lo2[tp];
            float2 hdd = dh2[tp], hb = h42[tp];
            *(float2*)&A[2*tp]  = make_float2(a.x - bvl.x, a.y - bvl.y);
            *(float2*)&Hs[2*tp] = make_float2(hdd.x - hb.x, hdd.y - hb.y);
        }
    }
    __syncthreads();

    {
        const int L = M4 - 5;
        int npairs = (L + 1) >> 1;   // 259
        for (int tp = tid; tp < npairs; tp += 256) {
            int jj = 2 * tp;
            const float2* a2 = (const float2*)(A + jj);
            const float2* h2 = (const float2*)(Hs + jj);
            float2 a0 = a2[0], a1 = a2[1], aq2 = a2[2];
            float2 h0 = h2[0], h1 = h2[1], hq2 = h2[2];
            float e0 = a0.x*c_dlo[1] + a0.y*c_dlo[3] + a1.x*c_dlo[5]
                     + a1.y*c_dlo[7] + aq2.x*c_dlo[9] + aq2.y*c_dlo[11]
                     + h0.x*c_dhi[1] + h0.y*c_dhi[3] + h1.x*c_dhi[5]
                     + h1.y*c_dhi[7] + hq2.x*c_dhi[9] + hq2.y*c_dhi[11];
            float od0= a0.x*c_dlo[0] + a0.y*c_dlo[2] + a1.x*c_dlo[4]
                     + a1.y*c_dlo[6] + aq2.x*c_dlo[8] + aq2.y*c_dlo[10]
                     + h0.x*c_dhi[0] + h0.y*c_dhi[2] + h1.x*c_dhi[4]
                     + h1.y*c_dhi[6] + hq2.x*c_dhi[8] + hq2.y*c_dhi[10];
            if (jj + 1 < L) {
                float2 a3 = a2[3], h3 = h2[3];
                float e1 = a0.y*c_dlo[1] + a1.x*c_dlo[3] + a1.y*c_dlo[5]
                         + aq2.x*c_dlo[7] + aq2.y*c_dlo[9] + a3.x*c_dlo[11]
                         + h0.y*c_dhi[1] + h1.x*c_dhi[3] + h1.y*c_dhi[5]
                         + hq2.x*c_dhi[7] + hq2.y*c_dhi[9] + h3.x*c_dhi[11];
                float od1= a0.y*c_dlo[0] + a1.x*c_dlo[2] + a1.y*c_dlo[4]
                         + aq2.x*c_dlo[6] + aq2.y*c_dlo[8] + a3.x*c_dlo[10]
                         + h0.y*c_dhi[0] + h1.x*c_dhi[2] + h1.y*c_dhi[4]
                         + hq2.x*c_dhi[6] + hq2.y*c_dhi[8] + h3.x*c_dhi[10];
                *(float4*)&B[2*jj] = make_float4(e0, od0, e1, od1);
            } else {
                B[2*jj] = e0; B[2*jj+1] = od0;
            }
        }
    }
    __syncthreads();

    ilvl_lo(B, A, M3 - 5, tid);
    __syncthreads();
    ilvl_lo(A, B, M2 - 5, tid);
    __syncthreads();

    {
        const float4* x4 = (const float4*)(x + (size_t)row * 8192);
        float4* o4 = (float4*)(out + (size_t)row * 8192);
        for (int tp = tid; tp < 2048; tp += 256) {
            int jj = 2 * tp;
            const float2* s2 = (const float2*)(B + jj);
            float2 q0 = s2[0], q1 = s2[1], q2 = s2[2], q3 = s2[3];
            float e0 = q0.x*c_dlo[1] + q0.y*c_dlo[3] + q1.x*c_dlo[5]
                     + q1.y*c_dlo[7] + q2.x*c_dlo[9] + q2.y*c_dlo[11];
            float od0= q0.x*c_dlo[0] + q0.y*c_dlo[2] + q1.x*c_dlo[4]
                     + q1.y*c_dlo[6] + q2.x*c_dlo[8] + q2.y*c_dlo[10];
            float e1 = q0.y*c_dlo[1] + q1.x*c_dlo[3] + q1.y*c_dlo[5]
                     + q2.x*c_dlo[7] + q2.y*c_dlo[9] + q3.x*c_dlo[11];
            float od1= q0.y*c_dlo[0] + q1.x*c_dlo[2] + q1.y*c_dlo[4]
                     + q2.x*c_dlo[6] + q2.y*c_dlo[8] + q3.x*c_dlo[10];
            float4 xv = x4[tp];
            o4[tp] = make_float4(xv.x + e0, xv.y + od0, xv.z + e1, xv.w + od1);
        }
    }
}

// Dual einsum v13b: full-k blocks, no barriers, wave-autonomous.
// dlo[b,o,k] += sum_{i in quarter} x[b,i,k]*w[i,o,k]
// Grid 1024: bid = oq*8 + e*4 + iq. Wave wv owns b = 4wv..4wv+3.
// Thread k-set: k = 2(l+64s)+{0,1}, s<4; lanes 0-4 own tail k = 512+2l(+1).
// Chunk indices are RELATIVE (xb0/wb0 already include i0) — r20's bug fixed.
__global__ __launch_bounds__(256, 3)
void einsum_v13(const ushort* __restrict__ xlT, const ushort* __restrict__ xhT,
                const float* __restrict__ w1,   const float* __restrict__ w2,
                float* __restrict__ dlo, float* __restrict__ dh)
{
    __shared__ __align__(16) ushort Xs[2][4][2048];   // [buf][wave][4KB] 32KB

    int bid = blockIdx.x;
    int oq = bid >> 3;
    int e  = (bid >> 2) & 1;
    int iq = bid & 3;
    const ushort* xT = e ? xhT : xlT;
    const float*  w  = e ? w2  : w1;
    float* outp      = e ? dh  : dlo;

    int l  = threadIdx.x & 63;
    int wv = threadIdx.x >> 6;
    int o  = oq * 2;
    int i0 = iq * 64;

    // x slab byte base for (c=i0, g=wv); per-i stride 16704 B
    const char* xb0 = (const char*)xT + ((size_t)i0 * 4 + wv) * 4176;
    const size_t XI = 16704;
    // w row float bases (i0, o) and (i0, o+1); per-i stride 133632 floats
    const float* wb0 = w + ((size_t)i0 * 256 + o) * 522;
    const float* wb1 = wb0 + 522;
    const size_t WI = (size_t)256 * 522;

    float acc[4][2][8];
    float act[4][2][2];
#pragma unroll
    for (int q = 0; q < 4; ++q)
#pragma unroll
        for (int j = 0; j < 2; ++j) {
#pragma unroll
            for (int k = 0; k < 8; ++k) acc[q][j][k] = 0.f;
            act[q][j][0] = 0.f; act[q][j][1] = 0.f;
        }

    float2 wA0[4], wA1[4], wB0[4], wB1[4];
    float2 wA0t, wA1t, wB0t, wB1t;
    uint4  xAt, xBt;

// CI is chunk-RELATIVE (0..63); xb0/wb0 already carry i0.
#define ISSUE(BUF, CI, W0, W1, W0T, W1T, XT_) do {                            \
    const char* xb_ = xb0 + (size_t)(CI) * XI;                                \
    gl16(xb_ +        (size_t)l * 16, &Xs[BUF][wv][0]);                       \
    gl16(xb_ + 1024 + (size_t)l * 16, &Xs[BUF][wv][512]);                     \
    gl16(xb_ + 2048 + (size_t)l * 16, &Xs[BUF][wv][1024]);                    \
    gl16(xb_ + 3072 + (size_t)l * 16, &Xs[BUF][wv][1536]);                    \
    __builtin_amdgcn_sched_barrier(0);                                        \
    const float* w0_ = wb0 + (size_t)(CI) * WI + 2 * l;                       \
    const float* w1_ = wb1 + (size_t)(CI) * WI + 2 * l;                       \
    W0[0] = *(const float2*)(w0_);        W1[0] = *(const float2*)(w1_);      \
    W0[1] = *(const float2*)(w0_ + 128);  W1[1] = *(const float2*)(w1_ + 128);\
    W0[2] = *(const float2*)(w0_ + 256);  W1[2] = *(const float2*)(w1_ + 256);\
    W0[3] = *(const float2*)(w0_ + 384);  W1[3] = *(const float2*)(w1_ + 384);\
    if (l < 5) {                                                              \
        W0T = *(const float2*)(wb0 + (size_t)(CI) * WI + 512 + 2 * l);        \
        W1T = *(const float2*)(wb1 + (size_t)(CI) * WI + 512 + 2 * l);        \
        XT_ = *(const uint4*)(xb_ + 4096 + (size_t)l * 16);                   \
    }                                                                         \
    __builtin_amdgcn_sched_barrier(0);                                        \
} while (0)

#define BL(u) __uint_as_float((u) << 16)
#define BH(u) __uint_as_float((u) & 0xffff0000u)

#define FMAS(S, XQ, W0, W1) do {                                              \
    float k0b0 = BL(XQ.x), k0b1 = BH(XQ.x), k0b2 = BL(XQ.y), k0b3 = BH(XQ.y);\
    float k1b0 = BL(XQ.z), k1b1 = BH(XQ.z), k1b2 = BL(XQ.w), k1b3 = BH(XQ.w);\
    acc[0][0][2*(S)]   += k0b0 * W0[S].x;  acc[0][0][2*(S)+1] += k1b0 * W0[S].y;\
    acc[1][0][2*(S)]   += k0b1 * W0[S].x;  acc[1][0][2*(S)+1] += k1b1 * W0[S].y;\
    acc[2][0][2*(S)]   += k0b2 * W0[S].x;  acc[2][0][2*(S)+1] += k1b2 * W0[S].y;\
    acc[3][0][2*(S)]   += k0b3 * W0[S].x;  acc[3][0][2*(S)+1] += k1b3 * W0[S].y;\
    acc[0][1][2*(S)]   += k0b0 * W1[S].x;  acc[0][1][2*(S)+1] += k1b0 * W1[S].y;\
    acc[1][1][2*(S)]   += k0b1 * W1[S].x;  acc[1][1][2*(S)+1] += k1b1 * W1[S].y;\
    acc[2][1][2*(S)]   += k0b2 * W1[S].x;  acc[2][1][2*(S)+1] += k1b2 * W1[S].y;\
    acc[3][1][2*(S)]   += k0b3 * W1[S].x;  acc[3][1][2*(S)+1] += k1b3 * W1[S].y;\
} while (0)

#define TFMAS(XT_, W0T, W1T) do {                                             \
    float t0b0 = BL(XT_.x), t0b1 = BH(XT_.x), t0b2 = BL(XT_.y), t0b3 = BH(XT_.y);\
    float t1b0 = BL(XT_.z), t1b1 = BH(XT_.z), t1b2 = BL(XT_.w), t1b3 = BH(XT_.w);\
    act[0][0][0] += t0b0 * W0T.x;  act[0][0][1] += t1b0 * W0T.y;              \
    act[1][0][0] += t0b1 * W0T.x;  act[1][0][1] += t1b1 * W0T.y;              \
    act[2][0][0] += t0b2 * W0T.x;  act[2][0][1] += t1b2 * W0T.y;              \
    act[3][0][0] += t0b3 * W0T.x;  act[3][0][1] += t1b3 * W0T.y;              \
    act[0][1][0] += t0b0 * W1T.x;  act[0][1][1] += t1b0 * W1T.y;              \
    act[1][1][0] += t0b1 * W1T.x;  act[1][1][1] += t1b1 * W1T.y;              \
    act[2][1][0] += t0b2 * W1T.x;  act[2][1][1] += t1b2 * W1T.y;              \
    act[3][1][0] += t0b3 * W1T.x;  act[3][1][1] += t1b3 * W1T.y;              \
} while (0)

#define CHUNK(BUF, CH, W0, W1, W0T, W1T, XT_) do {                            \
    if ((CH) < 63) asm volatile("s_waitcnt vmcnt(15)" ::: "memory");          \
    else           asm volatile("s_waitcnt vmcnt(0)"  ::: "memory");          \
    __builtin_amdgcn_sched_barrier(0);                                        \
    uint4 xq0 = *(const uint4*)&Xs[BUF][wv][l * 8];                           \
    uint4 xq1 = *(const uint4*)&Xs[BUF][wv][512 + l * 8];                     \
    uint4 xq2 = *(const uint4*)&Xs[BUF][wv][1024 + l * 8];                    \
    uint4 xq3 = *(const uint4*)&Xs[BUF][wv][1536 + l * 8];                    \
    asm volatile("s_waitcnt lgkmcnt(0)" ::: "memory");                        \
    __builtin_amdgcn_sched_barrier(0);                                        \
    FMAS(0, xq0, W0, W1);                                                     \
    FMAS(1, xq1, W0, W1);                                                     \
    FMAS(2, xq2, W0, W1);                                                     \
    FMAS(3, xq3, W0, W1);                                                     \
    TFMAS(XT_, W0T, W1T);                                                     \
    if ((CH) < 62) ISSUE(BUF, (CH) + 2, W0, W1, W0T, W1T, XT_);               \
} while (0)

    // prologue: groups 0,1 in flight (chunk-relative indices)
    ISSUE(0, 0, wA0, wA1, wA0t, wA1t, xAt);
    ISSUE(1, 1, wB0, wB1, wB0t, wB1t, xBt);

    for (int m = 0; m < 32; ++m) {
        int ch = 2 * m;
        CHUNK(0, ch,     wA0, wA1, wA0t, wA1t, xAt);
        CHUNK(1, ch + 1, wB0, wB1, wB0t, wB1t, xBt);
    }
#undef CHUNK
#undef ISSUE
#undef FMAS
#undef TFMAS
#undef BL
#undef BH

    // epilogue: atomicAdd (4 iq parts per element)
#pragma unroll
    for (int q = 0; q < 4; ++q) {
        int b = 4 * wv + q;
#pragma unroll
        for (int j = 0; j < 2; ++j) {
            float* op = outp + ((size_t)b * 256 + o + j) * MODES;
#pragma unroll
            for (int s = 0; s < 4; ++s) {
                int k = 2 * l + 128 * s;
                atomicAdd(op + k,     acc[q][j][2*s]);
                atomicAdd(op + k + 1, acc[q][j][2*s+1]);
            }
        }
    }
    if (l < 5) {
#pragma unroll
        for (int q = 0; q < 4; ++q) {
            int b = 4 * wv + q;
#pragma unroll
            for (int j = 0; j < 2; ++j) {
                float* op = outp + ((size_t)b * 256 + o + j) * MODES;
                atomicAdd(op + 512 + 2 * l,     act[q][j][0]);
                atomicAdd(op + 512 + 2 * l + 1, act[q][j][1]);
            }
        }
    }
}

extern "C" void kernel_launch(void* const* d_in, const int* in_sizes, int n_in,
                              void* d_out, int out_size, void* d_ws, size_t ws_size,
                              hipStream_t stream)
{
    const float* x  = (const float*)d_in[0];
    const float* w1 = (const float*)d_in[1];
    const float* w2 = (const float*)d_in[2];
    float* out = (float*)d_out;
    float* ws  = (float*)d_ws;

    const size_t SZ = (size_t)NROWS * M4;   // 2,138,112
    float* lo4 = ws;
    float* h4  = lo4 + SZ;
    float* dlo = h4  + SZ;
    float* dh  = dlo + SZ;                   // dlo,dh contiguous (zeroed together)
    ushort* xlT = (ushort*)(dh + SZ);        // SZ ushorts
    ushort* xhT = xlT + SZ;                  // SZ ushorts

    dim3 blk(256);

    dwt_fused3<<<NROWS, blk, 0, stream>>>(x, lo4, h4, xlT, xhT, dlo);
    einsum_v13<<<1024, blk, 0, stream>>>(xlT, xhT, w1, w2, dlo, dh);
    idwt_delta3<<<NROWS, blk, 0, stream>>>(dlo, dh, lo4, h4, x, out);
}

// Round 11
// 209.373 us; speedup vs baseline: 5.0904x; 5.0904x over previous
//
#include <hip/hip_runtime.h>

// WaveConv1d on MI355X — round 22: bank r8 build + dwt quad-vectorization.
//   out = x + idwt(E1(lo4)-lo4, E2(h4)-h4, 0, 0, 0)
// r21 post-mortem: v13b (page-sequential w, no barriers) = 974us @ 2.12 TB/s
// with 2.06 GB traffic (atomic RMW write-through + x re-fetch). SEVENTH
// structure pinned at ~2.1 TB/s => w's [i][o][k] layout (contraction over
// outer dim) forces island-streaming; einsum declared floored at v12's 102.8.
// This round: r8 build (202.3us) + dwt_lo QUADS (4 outputs/thread-iter from
// 9 float2 reads vs 2 from 7 — 36% fewer LDS reads on dwt's dominant phase).
// einsum_v12 + idwt_delta3 verbatim from r8.

#define NROWS 4096          // B*C
#define MODES 522

#define M1 4101
#define M2 2056
#define M3 1033
#define M4 522

typedef unsigned int  uint;
typedef unsigned short ushort;

__constant__ float c_dlo[12] = {
  -0.00107730108499558f,  0.004777257511010651f,  0.0005538422009938016f,
  -0.031582039318031156f, 0.02752286553001629f,   0.09750160558707936f,
  -0.12976686756709563f,  -0.22626469396516913f,  0.3152503517092432f,
   0.7511339080215775f,   0.4946238903983854f,    0.11154074335008017f };
__constant__ float c_dhi[12] = {
  -0.11154074335008017f,  0.4946238903983854f,   -0.7511339080215775f,
   0.3152503517092432f,   0.22626469396516913f,  -0.12976686756709563f,
  -0.09750160558707936f,  0.02752286553001629f,   0.031582039318031156f,
   0.0005538422009938016f,-0.004777257511010651f, -0.00107730108499558f };
// Analysis (time-reversed) filters
__constant__ float c_alo[12] = {
   0.11154074335008017f,  0.4946238903983854f,    0.7511339080215775f,
   0.3152503517092432f,  -0.22626469396516913f,  -0.12976686756709563f,
   0.09750160558707936f,  0.02752286553001629f,  -0.031582039318031156f,
   0.0005538422009938016f, 0.004777257511010651f, -0.00107730108499558f };
__constant__ float c_ahi[12] = {
  -0.00107730108499558f, -0.004777257511010651f,  0.0005538422009938016f,
   0.031582039318031156f, 0.02752286553001629f,  -0.09750160558707936f,
  -0.12976686756709563f,  0.22626469396516913f,   0.3152503517092432f,
  -0.7511339080215775f,   0.4946238903983854f,   -0.11154074335008017f };

__device__ __forceinline__ ushort f2bf(float f) {
    uint b = __float_as_uint(f);
    uint r = (b + 0x7fffu + ((b >> 16) & 1u)) >> 16;
    return (ushort)r;
}

// One lo-only analysis level LDS->LDS, QUAD-vectorized: thread computes
// outputs j0..j0+3 from 9 float2 LDS reads (window src[2j0-10 .. 2j0+7]);
// one float4 store. Boundary quads fall back to the scalar reflect path.
__device__ __forceinline__
void dwt_lo_quads(const float* __restrict__ src, int n, int m,
                  float* __restrict__ dst, int tid)
{
    int jhi = (n - 2) >> 1;
    int nquads = (m + 3) >> 2;
    for (int jq = tid; jq < nquads; jq += 256) {
        int j0 = 4 * jq;
        if (j0 >= 6 && j0 + 3 <= jhi && j0 + 3 < m) {
            const float2* s2 = (const float2*)(src + 2 * j0 - 10);
            float2 p0 = s2[0], p1 = s2[1], p2 = s2[2], p3 = s2[3], p4 = s2[4],
                   p5 = s2[5], p6 = s2[6], p7 = s2[7], p8 = s2[8];
            float a0 =
                p0.x*c_alo[0] + p0.y*c_alo[1] + p1.x*c_alo[2] + p1.y*c_alo[3] +
                p2.x*c_alo[4] + p2.y*c_alo[5] + p3.x*c_alo[6] + p3.y*c_alo[7] +
                p4.x*c_alo[8] + p4.y*c_alo[9] + p5.x*c_alo[10]+ p5.y*c_alo[11];
            float a1 =
                p1.x*c_alo[0] + p1.y*c_alo[1] + p2.x*c_alo[2] + p2.y*c_alo[3] +
                p3.x*c_alo[4] + p3.y*c_alo[5] + p4.x*c_alo[6] + p4.y*c_alo[7] +
                p5.x*c_alo[8] + p5.y*c_alo[9] + p6.x*c_alo[10]+ p6.y*c_alo[11];
            float a2 =
                p2.x*c_alo[0] + p2.y*c_alo[1] + p3.x*c_alo[2] + p3.y*c_alo[3] +
                p4.x*c_alo[4] + p4.y*c_alo[5] + p5.x*c_alo[6] + p5.y*c_alo[7] +
                p6.x*c_alo[8] + p6.y*c_alo[9] + p7.x*c_alo[10]+ p7.y*c_alo[11];
            float a3 =
                p3.x*c_alo[0] + p3.y*c_alo[1] + p4.x*c_alo[2] + p4.y*c_alo[3] +
                p5.x*c_alo[4] + p5.y*c_alo[5] + p6.x*c_alo[6] + p6.y*c_alo[7] +
                p7.x*c_alo[8] + p7.y*c_alo[9] + p8.x*c_alo[10]+ p8.y*c_alo[11];
            *(float4*)&dst[j0] = make_float4(a0, a1, a2, a3);
        } else {
#pragma unroll
            for (int q = 0; q < 4; ++q) {
                int j = j0 + q;
                if (j < m) {
                    int base = 2 * j - 10;
                    float a = 0.f;
#pragma unroll
                    for (int t = 0; t < 12; ++t) {
                        int u = base + t;
                        u = (u < 0) ? (-1 - u) : u;
                        u = (u >= n) ? (2 * n - 1 - u) : u;
                        a += src[u] * c_alo[t];
                    }
                    dst[j] = a;
                }
            }
        }
    }
}

// Fused forward DWT, lo-chain only: x -> (lo4, h4) fp32 AND bf16 xT
// [c][g4][k][b4] scattered stores. One block per row; row = b*256 + c.
__global__ __launch_bounds__(256)
void dwt_fused3(const float* __restrict__ x,
                float* __restrict__ lo4g, float* __restrict__ h4g,
                ushort* __restrict__ xlT, ushort* __restrict__ xhT)
{
    __shared__ float X[8192];
    __shared__ float LA[4104];
    int row = blockIdx.x, tid = threadIdx.x;

    const float4* xr = (const float4*)(x + (size_t)row * 8192);
    float4* Xv = (float4*)X;
#pragma unroll
    for (int i = 0; i < 8; ++i) Xv[tid + 256 * i] = xr[tid + 256 * i];
    __syncthreads();

    dwt_lo_quads(X,  8192, M1, LA, tid);
    __syncthreads();
    dwt_lo_quads(LA, M1,   M2, X,  tid);
    __syncthreads();
    dwt_lo_quads(X,  M2,   M3, LA, tid);
    __syncthreads();

    // level 4: dual filter, write lo4/h4 fp32 + xlT/xhT bf16 (scattered)
    float* lo4r = lo4g + (size_t)row * M4;
    float* h4r  = h4g  + (size_t)row * M4;
    int b  = row >> 8, c = row & 255;
    int cg = c * 4 + (b >> 2);
    int b4 = b & 3;
    int jhi = (M3 - 2) >> 1;            // 515
    for (int jp = tid; jp < 261; jp += 256) {
        int j0 = 2 * jp;                // j0+1 = 521 max, always a full pair
        float alo0, ahi0, alo1, ahi1;
        if (j0 >= 6 && j0 + 1 <= jhi) {
            const float2* s2 = (const float2*)(LA + 2 * j0 - 10);
            float2 p0 = s2[0], p1 = s2[1], p2 = s2[2], p3 = s2[3],
                   p4 = s2[4], p5 = s2[5], p6 = s2[6];
            alo0 =
                p0.x*c_alo[0] + p0.y*c_alo[1] + p1.x*c_alo[2] + p1.y*c_alo[3] +
                p2.x*c_alo[4] + p2.y*c_alo[5] + p3.x*c_alo[6] + p3.y*c_alo[7] +
                p4.x*c_alo[8] + p4.y*c_alo[9] + p5.x*c_alo[10]+ p5.y*c_alo[11];
            ahi0 =
                p0.x*c_ahi[0] + p0.y*c_ahi[1] + p1.x*c_ahi[2] + p1.y*c_ahi[3] +
                p2.x*c_ahi[4] + p2.y*c_ahi[5] + p3.x*c_ahi[6] + p3.y*c_ahi[7] +
                p4.x*c_ahi[8] + p4.y*c_ahi[9] + p5.x*c_ahi[10]+ p5.y*c_ahi[11];
            alo1 =
                p1.x*c_alo[0] + p1.y*c_alo[1] + p2.x*c_alo[2] + p2.y*c_alo[3] +
                p3.x*c_alo[4] + p3.y*c_alo[5] + p4.x*c_alo[6] + p4.y*c_alo[7] +
                p5.x*c_alo[8] + p5.y*c_alo[9] + p6.x*c_alo[10]+ p6.y*c_alo[11];
            ahi1 =
                p1.x*c_ahi[0] + p1.y*c_ahi[1] + p2.x*c_ahi[2] + p2.y*c_ahi[3] +
                p3.x*c_ahi[4] + p3.y*c_ahi[5] + p4.x*c_ahi[6] + p4.y*c_ahi[7] +
                p5.x*c_ahi[8] + p5.y*c_ahi[9] + p6.x*c_ahi[10]+ p6.y*c_ahi[11];
        } else {
#pragma unroll
            for (int q = 0; q < 2; ++q) {
                int base = 2 * (j0 + q) - 10;
                float al = 0.f, ah = 0.f;
#pragma unroll
                for (int t = 0; t < 12; ++t) {
                    int u = base + t;
                    u = (u < 0) ? (-1 - u) : u;
                    u = (u >= M3) ? (2 * M3 - 1 - u) : u;
                    float v = LA[u];
                    al += v * c_alo[t]; ah += v * c_ahi[t];
                }
                if (q == 0) { alo0 = al; ahi0 = ah; }
                else        { alo1 = al; ahi1 = ah; }
            }
        }
        *(float2*)&lo4r[j0] = make_float2(alo0, alo1);
        *(float2*)&h4r[j0]  = make_float2(ahi0, ahi1);
        size_t xi = ((size_t)cg * MODES + j0) * 4 + b4;
        xlT[xi]     = f2bf(alo0);
        xlT[xi + 4] = f2bf(alo1);
        xhT[xi]     = f2bf(ahi0);
        xhT[xi + 4] = f2bf(ahi1);
    }
}

// One synthesis (lo-only) level LDS->LDS, pair-vectorized.
__device__ __forceinline__
void ilvl_lo(const float* __restrict__ S, float* __restrict__ D,
             int L, int tid)
{
    int npairs = (L + 1) >> 1;
    for (int tp = tid; tp < npairs; tp += 256) {
        int jj = 2 * tp;
        const float2* s2 = (const float2*)(S + jj);
        float2 q0 = s2[0], q1 = s2[1], q2 = s2[2];
        float e0 = q0.x*c_dlo[1] + q0.y*c_dlo[3] + q1.x*c_dlo[5]
                 + q1.y*c_dlo[7] + q2.x*c_dlo[9] + q2.y*c_dlo[11];
        float od0= q0.x*c_dlo[0] + q0.y*c_dlo[2] + q1.x*c_dlo[4]
                 + q1.y*c_dlo[6] + q2.x*c_dlo[8] + q2.y*c_dlo[10];
        if (jj + 1 < L) {
            float2 q3 = s2[3];
            float e1 = q0.y*c_dlo[1] + q1.x*c_dlo[3] + q1.y*c_dlo[5]
                     + q2.x*c_dlo[7] + q2.y*c_dlo[9] + q3.x*c_dlo[11];
            float od1= q0.y*c_dlo[0] + q1.x*c_dlo[2] + q1.y*c_dlo[4]
                     + q2.x*c_dlo[6] + q2.y*c_dlo[8] + q3.x*c_dlo[10];
            *(float4*)&D[2*jj] = make_float4(e0, od0, e1, od1);
        } else {
            D[2*jj] = e0; D[2*jj+1] = od0;
        }
    }
}

// Delta-IDWT: A = dlo-lo4, Hs = dh-h4; lvl4 full -> lvl3,2,1 lo-only -> +x.
__global__ __launch_bounds__(256)
void idwt_delta3(const float* __restrict__ dlo, const float* __restrict__ dh,
                 const float* __restrict__ lo4, const float* __restrict__ h4,
                 const float* __restrict__ x,   float* __restrict__ out)
{
    __shared__ float A[2056];
    __shared__ float B[4104];
    __shared__ float Hs[528];
    int row = blockIdx.x, tid = threadIdx.x;

    {
        const float2* dl2 = (const float2*)(dlo + (size_t)row * M4);
        const float2* lo2 = (const float2*)(lo4 + (size_t)row * M4);
        const float2* dh2 = (const float2*)(dh  + (size_t)row * M4);
        const float2* h42 = (const float2*)(h4  + (size_t)row * M4);
        for (int tp = tid; tp < 261; tp += 256) {
            float2 a = dl2[tp], bvl = lo2[tp];
            float2 hdd = dh2[tp], hb = h42[tp];
            *(float2*)&A[2*tp]  = make_float2(a.x - bvl.x, a.y - bvl.y);
            *(float2*)&Hs[2*tp] = make_float2(hdd.x - hb.x, hdd.y - hb.y);
        }
    }
    __syncthreads();

    // level 4: dual input (A, Hs), L = M4-5 = 517
    {
        const int L = M4 - 5;
        int npairs = (L + 1) >> 1;   // 259
        for (int tp = tid; tp < npairs; tp += 256) {
            int jj = 2 * tp;
            const float2* a2 = (const float2*)(A + jj);
            const float2* h2 = (const float2*)(Hs + jj);
            float2 a0 = a2[0], a1 = a2[1], aq2 = a2[2];
            float2 h0 = h2[0], h1 = h2[1], hq2 = h2[2];
            float e0 = a0.x*c_dlo[1] + a0.y*c_dlo[3] + a1.x*c_dlo[5]
                     + a1.y*c_dlo[7] + aq2.x*c_dlo[9] + aq2.y*c_dlo[11]
                     + h0.x*c_dhi[1] + h0.y*c_dhi[3] + h1.x*c_dhi[5]
                     + h1.y*c_dhi[7] + hq2.x*c_dhi[9] + hq2.y*c_dhi[11];
            float od0= a0.x*c_dlo[0] + a0.y*c_dlo[2] + a1.x*c_dlo[4]
                     + a1.y*c_dlo[6] + aq2.x*c_dlo[8] + aq2.y*c_dlo[10]
                     + h0.x*c_dhi[0] + h0.y*c_dhi[2] + h1.x*c_dhi[4]
                     + h1.y*c_dhi[6] + hq2.x*c_dhi[8] + hq2.y*c_dhi[10];
            if (jj + 1 < L) {
                float2 a3 = a2[3], h3 = h2[3];
                float e1 = a0.y*c_dlo[1] + a1.x*c_dlo[3] + a1.y*c_dlo[5]
                         + aq2.x*c_dlo[7] + aq2.y*c_dlo[9] + a3.x*c_dlo[11]
                         + h0.y*c_dhi[1] + h1.x*c_dhi[3] + h1.y*c_dhi[5]
                         + hq2.x*c_dhi[7] + hq2.y*c_dhi[9] + h3.x*c_dhi[11];
                float od1= a0.y*c_dlo[0] + a1.x*c_dlo[2] + a1.y*c_dlo[4]
                         + aq2.x*c_dlo[6] + aq2.y*c_dlo[8] + a3.x*c_dlo[10]
                         + h0.y*c_dhi[0] + h1.x*c_dhi[2] + h1.y*c_dhi[4]
                         + hq2.x*c_dhi[6] + hq2.y*c_dhi[8] + h3.x*c_dhi[10];
                *(float4*)&B[2*jj] = make_float4(e0, od0, e1, od1);
            } else {
                B[2*jj] = e0; B[2*jj+1] = od0;
            }
        }
    }
    __syncthreads();

    ilvl_lo(B, A, M3 - 5, tid);      // -> A[0..2055]
    __syncthreads();
    ilvl_lo(A, B, M2 - 5, tid);      // -> B[0..4101]
    __syncthreads();

    // final level: L = M1-5 = 4096 (even -> always full pairs), fused +x.
    {
        const float4* x4 = (const float4*)(x + (size_t)row * 8192);
        float4* o4 = (float4*)(out + (size_t)row * 8192);
        for (int tp = tid; tp < 2048; tp += 256) {
            int jj = 2 * tp;
            const float2* s2 = (const float2*)(B + jj);
            float2 q0 = s2[0], q1 = s2[1], q2 = s2[2], q3 = s2[3];
            float e0 = q0.x*c_dlo[1] + q0.y*c_dlo[3] + q1.x*c_dlo[5]
                     + q1.y*c_dlo[7] + q2.x*c_dlo[9] + q2.y*c_dlo[11];
            float od0= q0.x*c_dlo[0] + q0.y*c_dlo[2] + q1.x*c_dlo[4]
                     + q1.y*c_dlo[6] + q2.x*c_dlo[8] + q2.y*c_dlo[10];
            float e1 = q0.y*c_dlo[1] + q1.x*c_dlo[3] + q1.y*c_dlo[5]
                     + q2.x*c_dlo[7] + q2.y*c_dlo[9] + q3.x*c_dlo[11];
            float od1= q0.y*c_dlo[0] + q1.x*c_dlo[2] + q1.y*c_dlo[4]
                     + q2.x*c_dlo[6] + q2.y*c_dlo[8] + q3.x*c_dlo[10];
            float4 xv = x4[tp];
            o4[tp] = make_float4(xv.x + e0, xv.y + od0, xv.z + e1, xv.w + od1);
        }
    }
}

// Dual einsum v12 (verbatim r8, measured 102.8us): k-tile 128 main blocks +
// verbatim-v5 tail blocks. dlo[b,o,k] = sum_i x[b,i,k]*w[i,o,k].
__global__ __launch_bounds__(256)
void einsum_v12(const ushort* __restrict__ xlT, const ushort* __restrict__ xhT,
                const float* __restrict__ w1,   const float* __restrict__ w2,
                float* __restrict__ dlo, float* __restrict__ dh)
{
    __shared__ ushort Xb[2][8192];   // main: [buf][((il*4+g)*128+k)*4+b] 32 KB
    __shared__ float  Wb[2][2048];   // main: [buf][(il*4+j)*128+k]       16 KB

    int bid  = blockIdx.x;
    int lane = threadIdx.x & 63;
    int wv   = threadIdx.x >> 6;
    int t    = threadIdx.x;

    if (bid < 512) {
        // ================= main path: k-width 128 =================
        int kt2 = bid & 3;
        int e   = (bid >> 2) & 1;
        int oq  = bid >> 3;
        const ushort* xT = e ? xhT : xlT;
        const float*  w  = e ? w2  : w1;
        float* outp      = e ? dh  : dlo;
        int o     = oq * 4;
        int kbase = kt2 * 128;

        const ushort* xg0 = xT + (((size_t)wv * 4 + 0) * MODES + kbase) * 4 + lane * 8;
        const ushort* xg1 = xT + (((size_t)wv * 4 + 1) * MODES + kbase) * 4 + lane * 8;
        const ushort* xg2 = xT + (((size_t)wv * 4 + 2) * MODES + kbase) * 4 + lane * 8;
        const ushort* xg3 = xT + (((size_t)wv * 4 + 3) * MODES + kbase) * 4 + lane * 8;
        const size_t XCH = (size_t)4 * 4 * MODES * 4;   // ushorts per chunk (4 i)
        const float* wj0 = w + ((size_t)wv * 256 + o + 0) * MODES + kbase + lane * 2;
        const float* wj1 = w + ((size_t)wv * 256 + o + 1) * MODES + kbase + lane * 2;
        const float* wj2 = w + ((size_t)wv * 256 + o + 2) * MODES + kbase + lane * 2;
        const float* wj3 = w + ((size_t)wv * 256 + o + 3) * MODES + kbase + lane * 2;
        const size_t WCH = (size_t)4 * 256 * MODES;     // floats per chunk

        float acc[4][4][2];
#pragma unroll
        for (int q = 0; q < 4; ++q)
#pragma unroll
            for (int j = 0; j < 4; ++j) { acc[q][j][0] = 0.f; acc[q][j][1] = 0.f; }

        uint4  xv0, xv1, xv2, xv3;
        float2 wv0, wv1, wv2, wv3;

#define LOADCH(CH) do {                                                       \
        size_t xo_ = (size_t)(CH) * XCH;                                      \
        xv0 = *(const uint4*)(xg0 + xo_); xv1 = *(const uint4*)(xg1 + xo_);   \
        xv2 = *(const uint4*)(xg2 + xo_); xv3 = *(const uint4*)(xg3 + xo_);   \
        size_t wo_ = (size_t)(CH) * WCH;                                      \
        wv0 = *(const float2*)(wj0 + wo_); wv1 = *(const float2*)(wj1 + wo_); \
        wv2 = *(const float2*)(wj2 + wo_); wv3 = *(const float2*)(wj3 + wo_); \
    } while (0)

#define WRITECH(NB) do {                                                      \
        *(uint4*)&Xb[NB][(wv * 4 + 0) * 512 + lane * 8] = xv0;                \
        *(uint4*)&Xb[NB][(wv * 4 + 1) * 512 + lane * 8] = xv1;                \
        *(uint4*)&Xb[NB][(wv * 4 + 2) * 512 + lane * 8] = xv2;                \
        *(uint4*)&Xb[NB][(wv * 4 + 3) * 512 + lane * 8] = xv3;                \
        *(float2*)&Wb[NB][(wv * 4 + 0) * 128 + lane * 2] = wv0;               \
        *(float2*)&Wb[NB][(wv * 4 + 1) * 128 + lane * 2] = wv1;               \
        *(float2*)&Wb[NB][(wv * 4 + 2) * 128 + lane * 2] = wv2;               \
        *(float2*)&Wb[NB][(wv * 4 + 3) * 128 + lane * 2] = wv3;               \
    } while (0)

        LOADCH(0);
        WRITECH(0);
        __syncthreads();

        for (int ch = 0; ch < 64; ++ch) {
            int cur = ch & 1, nb = cur ^ 1;
            if (ch < 63) LOADCH(ch + 1);

#pragma unroll
            for (int ii = 0; ii < 4; ++ii) {
                uint4 xq = *(const uint4*)&Xb[cur][((ii * 4 + wv) * 128 + 2 * lane) * 4];
                float x00 = __uint_as_float(xq.x << 16);
                float x01 = __uint_as_float(xq.x & 0xffff0000u);
                float x02 = __uint_as_float(xq.y << 16);
                float x03 = __uint_as_float(xq.y & 0xffff0000u);
                float x10 = __uint_as_float(xq.z << 16);
                float x11 = __uint_as_float(xq.z & 0xffff0000u);
                float x12 = __uint_as_float(xq.w << 16);
                float x13 = __uint_as_float(xq.w & 0xffff0000u);
                float2 wq0 = *(const float2*)&Wb[cur][(ii * 4 + 0) * 128 + 2 * lane];
                float2 wq1 = *(const float2*)&Wb[cur][(ii * 4 + 1) * 128 + 2 * lane];
                float2 wq2 = *(const float2*)&Wb[cur][(ii * 4 + 2) * 128 + 2 * lane];
                float2 wq3 = *(const float2*)&Wb[cur][(ii * 4 + 3) * 128 + 2 * lane];
                acc[0][0][0] += x00 * wq0.x; acc[0][0][1] += x10 * wq0.y;
                acc[0][1][0] += x00 * wq1.x; acc[0][1][1] += x10 * wq1.y;
                acc[0][2][0] += x00 * wq2.x; acc[0][2][1] += x10 * wq2.y;
                acc[0][3][0] += x00 * wq3.x; acc[0][3][1] += x10 * wq3.y;
                acc[1][0][0] += x01 * wq0.x; acc[1][0][1] += x11 * wq0.y;
                acc[1][1][0] += x01 * wq1.x; acc[1][1][1] += x11 * wq1.y;
                acc[1][2][0] += x01 * wq2.x; acc[1][2][1] += x11 * wq2.y;
                acc[1][3][0] += x01 * wq3.x; acc[1][3][1] += x11 * wq3.y;
                acc[2][0][0] += x02 * wq0.x; acc[2][0][1] += x12 * wq0.y;
                acc[2][1][0] += x02 * wq1.x; acc[2][1][1] += x12 * wq1.y;
                acc[2][2][0] += x02 * wq2.x; acc[2][2][1] += x12 * wq2.y;
                acc[2][3][0] += x02 * wq3.x; acc[2][3][1] += x12 * wq3.y;
                acc[3][0][0] += x03 * wq0.x; acc[3][0][1] += x13 * wq0.y;
                acc[3][1][0] += x03 * wq1.x; acc[3][1][1] += x13 * wq1.y;
                acc[3][2][0] += x03 * wq2.x; acc[3][2][1] += x13 * wq2.y;
                acc[3][3][0] += x03 * wq3.x; acc[3][3][1] += x13 * wq3.y;
            }

            if (ch < 63) WRITECH(nb);
            __syncthreads();
        }
#undef LOADCH
#undef WRITECH

#pragma unroll
        for (int q = 0; q < 4; ++q) {
            int b = 4 * wv + q;
#pragma unroll
            for (int j = 0; j < 4; ++j)
                *(float2*)&outp[((size_t)b * 256 + o + j) * MODES + kbase + 2 * lane]
                    = make_float2(acc[q][j][0], acc[q][j][1]);
        }
    } else {
        // ================= tail path: verbatim v5, kbase=458 =================
        int tb = bid - 512;
        int e  = tb >> 6;
        int oq = tb & 63;
        const ushort* xT = e ? xhT : xlT;
        const float*  w  = e ? w2  : w1;
        float* outp      = e ? dh  : dlo;
        int kbase = MODES - 64;   // 458
        int o     = oq * 4;

        int run = t >> 4, piece = t & 15;
        int il = run >> 2, sub = run & 3;

        const ushort* xrunb = xT + (((size_t)il * 4 + sub) * MODES + kbase) * 4 + piece * 16;
        const size_t xistr = (size_t)4 * MODES * 4;
        const float* wrunb = w + ((size_t)il * 256 + o + sub) * MODES + kbase + piece * 4;
        const size_t wistr = (size_t)256 * MODES;

        float acc[4][4];
#pragma unroll
        for (int q = 0; q < 4; ++q)
#pragma unroll
            for (int j = 0; j < 4; ++j) acc[q][j] = 0.f;

        {
            uint4 v0 = *(const uint4*)(xrunb);
            uint4 v1 = *(const uint4*)(xrunb + 8);
            float f0 = wrunb[0], f1 = wrunb[1], f2 = wrunb[2], f3 = wrunb[3];
            uint4* xd = (uint4*)&Xb[0][t * 16];
            xd[0] = v0; xd[1] = v1;
            float4* wd = (float4*)&Wb[0][t * 4];
            *wd = make_float4(f0, f1, f2, f3);
        }
        __syncthreads();

        for (int ch = 0; ch < 64; ++ch) {
            int cur = ch & 1, nb = cur ^ 1;
            uint4 v0, v1; float f0, f1, f2, f3;
            if (ch < 63) {
                const ushort* xs = xrunb + (size_t)(ch + 1) * 4 * xistr;
                v0 = *(const uint4*)(xs);
                v1 = *(const uint4*)(xs + 8);
                const float* wsv = wrunb + (size_t)(ch + 1) * 4 * wistr;
                f0 = wsv[0]; f1 = wsv[1]; f2 = wsv[2]; f3 = wsv[3];
            }

#pragma unroll
            for (int ii = 0; ii < 4; ++ii) {
                uint2 xp = *(const uint2*)&Xb[cur][(((ii * 4) + wv) * 64 + lane) * 4];
                float x0 = __uint_as_float(xp.x << 16);
                float x1 = __uint_as_float(xp.x & 0xffff0000u);
                float x2 = __uint_as_float(xp.y << 16);
                float x3 = __uint_as_float(xp.y & 0xffff0000u);
                float wr0 = Wb[cur][(ii * 4 + 0) * 64 + lane];
                float wr1 = Wb[cur][(ii * 4 + 1) * 64 + lane];
                float wr2 = Wb[cur][(ii * 4 + 2) * 64 + lane];
                float wr3 = Wb[cur][(ii * 4 + 3) * 64 + lane];
                acc[0][0] += x0 * wr0; acc[0][1] += x0 * wr1;
                acc[0][2] += x0 * wr2; acc[0][3] += x0 * wr3;
                acc[1][0] += x1 * wr0; acc[1][1] += x1 * wr1;
                acc[1][2] += x1 * wr2; acc[1][3] += x1 * wr3;
                acc[2][0] += x2 * wr0; acc[2][1] += x2 * wr1;
                acc[2][2] += x2 * wr2; acc[2][3] += x2 * wr3;
                acc[3][0] += x3 * wr0; acc[3][1] += x3 * wr1;
                acc[3][2] += x3 * wr2; acc[3][3] += x3 * wr3;
            }

            if (ch < 63) {
                uint4* xd = (uint4*)&Xb[nb][t * 16];
                xd[0] = v0; xd[1] = v1;
                float4* wd = (float4*)&Wb[nb][t * 4];
                *wd = make_float4(f0, f1, f2, f3);
            }
            __syncthreads();
        }

#pragma unroll
        for (int q = 0; q < 4; ++q) {
            int b = 4 * wv + q;
#pragma unroll
            for (int j = 0; j < 4; ++j)
                outp[((size_t)b * 256 + o + j) * MODES + kbase + lane] = acc[q][j];
        }
    }
}

extern "C" void kernel_launch(void* const* d_in, const int* in_sizes, int n_in,
                              void* d_out, int out_size, void* d_ws, size_t ws_size,
                              hipStream_t stream)
{
    const float* x  = (const float*)d_in[0];
    const float* w1 = (const float*)d_in[1];
    const float* w2 = (const float*)d_in[2];
    float* out = (float*)d_out;
    float* ws  = (float*)d_ws;

    const size_t SZ = (size_t)NROWS * M4;   // 2,138,112
    float* lo4 = ws;
    float* h4  = lo4 + SZ;
    float* dlo = h4  + SZ;
    float* dh  = dlo + SZ;
    ushort* xlT = (ushort*)(dh + SZ);        // SZ ushorts
    ushort* xhT = xlT + SZ;                  // SZ ushorts

    dim3 blk(256);

    dwt_fused3<<<NROWS, blk, 0, stream>>>(x, lo4, h4, xlT, xhT);
    einsum_v12<<<640, blk, 0, stream>>>(xlT, xhT, w1, w2, dlo, dh);
    idwt_delta3<<<NROWS, blk, 0, stream>>>(dlo, dh, lo4, h4, x, out);
}

// Round 12
// 202.153 us; speedup vs baseline: 5.2723x; 1.0357x over previous
//
#include <hip/hip_runtime.h>

// WaveConv1d on MI355X — round 23: revert to the round-8 build (202.3us).
//   out = x + idwt(E1(lo4)-lo4, E2(h4)-h4, 0, 0, 0)
// r22 post-mortem: dwt quad-vectorization REGRESSED (202.3 -> 209.4us).
// Cause: quad doubles LDS lane stride 16B->32B => bank stride 4->8 => 16-way
// conflicts (vs 8-way for pairs); instruction-count saving (36%) < conflict
// cost. The per-instruction read-address SET is fixed by the sliding-window
// mapping, so only a swizzled level-array layout could fix it — not worth it
// without dwt-specific counter evidence. Reverting to the proven r8 build:
//   dwt_fused3 (pair-vectorized levels, fused bf16 xT emission)
//   einsum_v12 (k-tile 128 main + v5 tail; 102.8us measured)
//   idwt_delta3 (pair-vectorized synthesis, fused +x)
// Session summary: einsum floored at ~103us (7 structures all pinned at
// ~2.1-2.7 TB/s w-stream; w [i][o][k] layout island-streaming is structural).

#define NROWS 4096          // B*C
#define MODES 522

#define M1 4101
#define M2 2056
#define M3 1033
#define M4 522

typedef unsigned int  uint;
typedef unsigned short ushort;

__constant__ float c_dlo[12] = {
  -0.00107730108499558f,  0.004777257511010651f,  0.0005538422009938016f,
  -0.031582039318031156f, 0.02752286553001629f,   0.09750160558707936f,
  -0.12976686756709563f,  -0.22626469396516913f,  0.3152503517092432f,
   0.7511339080215775f,   0.4946238903983854f,    0.11154074335008017f };
__constant__ float c_dhi[12] = {
  -0.11154074335008017f,  0.4946238903983854f,   -0.7511339080215775f,
   0.3152503517092432f,   0.22626469396516913f,  -0.12976686756709563f,
  -0.09750160558707936f,  0.02752286553001629f,   0.031582039318031156f,
   0.0005538422009938016f,-0.004777257511010651f, -0.00107730108499558f };
// Analysis (time-reversed) filters
__constant__ float c_alo[12] = {
   0.11154074335008017f,  0.4946238903983854f,    0.7511339080215775f,
   0.3152503517092432f,  -0.22626469396516913f,  -0.12976686756709563f,
   0.09750160558707936f,  0.02752286553001629f,  -0.031582039318031156f,
   0.0005538422009938016f, 0.004777257511010651f, -0.00107730108499558f };
__constant__ float c_ahi[12] = {
  -0.00107730108499558f, -0.004777257511010651f,  0.0005538422009938016f,
   0.031582039318031156f, 0.02752286553001629f,  -0.09750160558707936f,
  -0.12976686756709563f,  0.22626469396516913f,   0.3152503517092432f,
  -0.7511339080215775f,   0.4946238903983854f,   -0.11154074335008017f };

__device__ __forceinline__ ushort f2bf(float f) {
    uint b = __float_as_uint(f);
    uint r = (b + 0x7fffu + ((b >> 16) & 1u)) >> 16;
    return (ushort)r;
}

// One lo-only analysis level LDS->LDS, PAIR-vectorized: thread computes
// outputs (j0, j0+1) from 7 float2 LDS reads (window src[2j0-10 .. 2j0+3]).
__device__ __forceinline__
void dwt_lo_pairs(const float* __restrict__ src, int n, int m,
                  float* __restrict__ dst, int tid)
{
    int jhi = (n - 2) >> 1;
    int npairs = (m + 1) >> 1;
    for (int jp = tid; jp < npairs; jp += 256) {
        int j0 = 2 * jp;
        if (j0 >= 6 && j0 + 1 <= jhi) {
            const float2* s2 = (const float2*)(src + 2 * j0 - 10);
            float2 p0 = s2[0], p1 = s2[1], p2 = s2[2], p3 = s2[3],
                   p4 = s2[4], p5 = s2[5], p6 = s2[6];
            float a0 =
                p0.x*c_alo[0] + p0.y*c_alo[1] + p1.x*c_alo[2] + p1.y*c_alo[3] +
                p2.x*c_alo[4] + p2.y*c_alo[5] + p3.x*c_alo[6] + p3.y*c_alo[7] +
                p4.x*c_alo[8] + p4.y*c_alo[9] + p5.x*c_alo[10]+ p5.y*c_alo[11];
            float a1 =
                p1.x*c_alo[0] + p1.y*c_alo[1] + p2.x*c_alo[2] + p2.y*c_alo[3] +
                p3.x*c_alo[4] + p3.y*c_alo[5] + p4.x*c_alo[6] + p4.y*c_alo[7] +
                p5.x*c_alo[8] + p5.y*c_alo[9] + p6.x*c_alo[10]+ p6.y*c_alo[11];
            *(float2*)&dst[j0] = make_float2(a0, a1);
        } else {
#pragma unroll
            for (int q = 0; q < 2; ++q) {
                int j = j0 + q;
                if (j < m) {
                    int base = 2 * j - 10;
                    float a = 0.f;
#pragma unroll
                    for (int t = 0; t < 12; ++t) {
                        int u = base + t;
                        u = (u < 0) ? (-1 - u) : u;
                        u = (u >= n) ? (2 * n - 1 - u) : u;
                        a += src[u] * c_alo[t];
                    }
                    dst[j] = a;
                }
            }
        }
    }
}

// Fused forward DWT, lo-chain only: x -> (lo4, h4) fp32 AND bf16 xT
// [c][g4][k][b4] scattered stores. One block per row; row = b*256 + c.
__global__ __launch_bounds__(256)
void dwt_fused3(const float* __restrict__ x,
                float* __restrict__ lo4g, float* __restrict__ h4g,
                ushort* __restrict__ xlT, ushort* __restrict__ xhT)
{
    __shared__ float X[8192];
    __shared__ float LA[4104];
    int row = blockIdx.x, tid = threadIdx.x;

    const float4* xr = (const float4*)(x + (size_t)row * 8192);
    float4* Xv = (float4*)X;
#pragma unroll
    for (int i = 0; i < 8; ++i) Xv[tid + 256 * i] = xr[tid + 256 * i];
    __syncthreads();

    dwt_lo_pairs(X,  8192, M1, LA, tid);
    __syncthreads();
    dwt_lo_pairs(LA, M1,   M2, X,  tid);
    __syncthreads();
    dwt_lo_pairs(X,  M2,   M3, LA, tid);
    __syncthreads();

    // level 4: dual filter, write lo4/h4 fp32 + xlT/xhT bf16 (scattered)
    float* lo4r = lo4g + (size_t)row * M4;
    float* h4r  = h4g  + (size_t)row * M4;
    int b  = row >> 8, c = row & 255;
    int cg = c * 4 + (b >> 2);
    int b4 = b & 3;
    int jhi = (M3 - 2) >> 1;            // 515
    for (int jp = tid; jp < 261; jp += 256) {
        int j0 = 2 * jp;                // j0+1 = 521 max, always a full pair
        float alo0, ahi0, alo1, ahi1;
        if (j0 >= 6 && j0 + 1 <= jhi) {
            const float2* s2 = (const float2*)(LA + 2 * j0 - 10);
            float2 p0 = s2[0], p1 = s2[1], p2 = s2[2], p3 = s2[3],
                   p4 = s2[4], p5 = s2[5], p6 = s2[6];
            alo0 =
                p0.x*c_alo[0] + p0.y*c_alo[1] + p1.x*c_alo[2] + p1.y*c_alo[3] +
                p2.x*c_alo[4] + p2.y*c_alo[5] + p3.x*c_alo[6] + p3.y*c_alo[7] +
                p4.x*c_alo[8] + p4.y*c_alo[9] + p5.x*c_alo[10]+ p5.y*c_alo[11];
            ahi0 =
                p0.x*c_ahi[0] + p0.y*c_ahi[1] + p1.x*c_ahi[2] + p1.y*c_ahi[3] +
                p2.x*c_ahi[4] + p2.y*c_ahi[5] + p3.x*c_ahi[6] + p3.y*c_ahi[7] +
                p4.x*c_ahi[8] + p4.y*c_ahi[9] + p5.x*c_ahi[10]+ p5.y*c_ahi[11];
            alo1 =
                p1.x*c_alo[0] + p1.y*c_alo[1] + p2.x*c_alo[2] + p2.y*c_alo[3] +
                p3.x*c_alo[4] + p3.y*c_alo[5] + p4.x*c_alo[6] + p4.y*c_alo[7] +
                p5.x*c_alo[8] + p5.y*c_alo[9] + p6.x*c_alo[10]+ p6.y*c_alo[11];
            ahi1 =
                p1.x*c_ahi[0] + p1.y*c_ahi[1] + p2.x*c_ahi[2] + p2.y*c_ahi[3] +
                p3.x*c_ahi[4] + p3.y*c_ahi[5] + p4.x*c_ahi[6] + p4.y*c_ahi[7] +
                p5.x*c_ahi[8] + p5.y*c_ahi[9] + p6.x*c_ahi[10]+ p6.y*c_ahi[11];
        } else {
#pragma unroll
            for (int q = 0; q < 2; ++q) {
                int base = 2 * (j0 + q) - 10;
                float al = 0.f, ah = 0.f;
#pragma unroll
                for (int t = 0; t < 12; ++t) {
                    int u = base + t;
                    u = (u < 0) ? (-1 - u) : u;
                    u = (u >= M3) ? (2 * M3 - 1 - u) : u;
                    float v = LA[u];
                    al += v * c_alo[t]; ah += v * c_ahi[t];
                }
                if (q == 0) { alo0 = al; ahi0 = ah; }
                else        { alo1 = al; ahi1 = ah; }
            }
        }
        *(float2*)&lo4r[j0] = make_float2(alo0, alo1);
        *(float2*)&h4r[j0]  = make_float2(ahi0, ahi1);
        size_t xi = ((size_t)cg * MODES + j0) * 4 + b4;
        xlT[xi]     = f2bf(alo0);
        xlT[xi + 4] = f2bf(alo1);
        xhT[xi]     = f2bf(ahi0);
        xhT[xi + 4] = f2bf(ahi1);
    }
}

// One synthesis (lo-only) level LDS->LDS, pair-vectorized.
__device__ __forceinline__
void ilvl_lo(const float* __restrict__ S, float* __restrict__ D,
             int L, int tid)
{
    int npairs = (L + 1) >> 1;
    for (int tp = tid; tp < npairs; tp += 256) {
        int jj = 2 * tp;
        const float2* s2 = (const float2*)(S + jj);
        float2 q0 = s2[0], q1 = s2[1], q2 = s2[2];
        float e0 = q0.x*c_dlo[1] + q0.y*c_dlo[3] + q1.x*c_dlo[5]
                 + q1.y*c_dlo[7] + q2.x*c_dlo[9] + q2.y*c_dlo[11];
        float od0= q0.x*c_dlo[0] + q0.y*c_dlo[2] + q1.x*c_dlo[4]
                 + q1.y*c_dlo[6] + q2.x*c_dlo[8] + q2.y*c_dlo[10];
        if (jj + 1 < L) {
            float2 q3 = s2[3];
            float e1 = q0.y*c_dlo[1] + q1.x*c_dlo[3] + q1.y*c_dlo[5]
                     + q2.x*c_dlo[7] + q2.y*c_dlo[9] + q3.x*c_dlo[11];
            float od1= q0.y*c_dlo[0] + q1.x*c_dlo[2] + q1.y*c_dlo[4]
                     + q2.x*c_dlo[6] + q2.y*c_dlo[8] + q3.x*c_dlo[10];
            *(float4*)&D[2*jj] = make_float4(e0, od0, e1, od1);
        } else {
            D[2*jj] = e0; D[2*jj+1] = od0;
        }
    }
}

// Delta-IDWT: A = dlo-lo4, Hs = dh-h4; lvl4 full -> lvl3,2,1 lo-only -> +x.
__global__ __launch_bounds__(256)
void idwt_delta3(const float* __restrict__ dlo, const float* __restrict__ dh,
                 const float* __restrict__ lo4, const float* __restrict__ h4,
                 const float* __restrict__ x,   float* __restrict__ out)
{
    __shared__ float A[2056];
    __shared__ float B[4104];
    __shared__ float Hs[528];
    int row = blockIdx.x, tid = threadIdx.x;

    {
        const float2* dl2 = (const float2*)(dlo + (size_t)row * M4);
        const float2* lo2 = (const float2*)(lo4 + (size_t)row * M4);
        const float2* dh2 = (const float2*)(dh  + (size_t)row * M4);
        const float2* h42 = (const float2*)(h4  + (size_t)row * M4);
        for (int tp = tid; tp < 261; tp += 256) {
            float2 a = dl2[tp], bvl = lo2[tp];
            float2 hdd = dh2[tp], hb = h42[tp];
            *(float2*)&A[2*tp]  = make_float2(a.x - bvl.x, a.y - bvl.y);
            *(float2*)&Hs[2*tp] = make_float2(hdd.x - hb.x, hdd.y - hb.y);
        }
    }
    __syncthreads();

    // level 4: dual input (A, Hs), L = M4-5 = 517
    {
        const int L = M4 - 5;
        int npairs = (L + 1) >> 1;   // 259
        for (int tp = tid; tp < npairs; tp += 256) {
            int jj = 2 * tp;
            const float2* a2 = (const float2*)(A + jj);
            const float2* h2 = (const float2*)(Hs + jj);
            float2 a0 = a2[0], a1 = a2[1], aq2 = a2[2];
            float2 h0 = h2[0], h1 = h2[1], hq2 = h2[2];
            float e0 = a0.x*c_dlo[1] + a0.y*c_dlo[3] + a1.x*c_dlo[5]
                     + a1.y*c_dlo[7] + aq2.x*c_dlo[9] + aq2.y*c_dlo[11]
                     + h0.x*c_dhi[1] + h0.y*c_dhi[3] + h1.x*c_dhi[5]
                     + h1.y*c_dhi[7] + hq2.x*c_dhi[9] + hq2.y*c_dhi[11];
            float od0= a0.x*c_dlo[0] + a0.y*c_dlo[2] + a1.x*c_dlo[4]
                     + a1.y*c_dlo[6] + aq2.x*c_dlo[8] + aq2.y*c_dlo[10]
                     + h0.x*c_dhi[0] + h0.y*c_dhi[2] + h1.x*c_dhi[4]
                     + h1.y*c_dhi[6] + hq2.x*c_dhi[8] + hq2.y*c_dhi[10];
            if (jj + 1 < L) {
                float2 a3 = a2[3], h3 = h2[3];
                float e1 = a0.y*c_dlo[1] + a1.x*c_dlo[3] + a1.y*c_dlo[5]
                         + aq2.x*c_dlo[7] + aq2.y*c_dlo[9] + a3.x*c_dlo[11]
                         + h0.y*c_dhi[1] + h1.x*c_dhi[3] + h1.y*c_dhi[5]
                         + hq2.x*c_dhi[7] + hq2.y*c_dhi[9] + h3.x*c_dhi[11];
                float od1= a0.y*c_dlo[0] + a1.x*c_dlo[2] + a1.y*c_dlo[4]
                         + aq2.x*c_dlo[6] + aq2.y*c_dlo[8] + a3.x*c_dlo[10]
                         + h0.y*c_dhi[0] + h1.x*c_dhi[2] + h1.y*c_dhi[4]
                         + hq2.x*c_dhi[6] + hq2.y*c_dhi[8] + h3.x*c_dhi[10];
                *(float4*)&B[2*jj] = make_float4(e0, od0, e1, od1);
            } else {
                B[2*jj] = e0; B[2*jj+1] = od0;
            }
        }
    }
    __syncthreads();

    ilvl_lo(B, A, M3 - 5, tid);      // -> A[0..2055]
    __syncthreads();
    ilvl_lo(A, B, M2 - 5, tid);      // -> B[0..4101]
    __syncthreads();

    // final level: L = M1-5 = 4096 (even -> always full pairs), fused +x.
    {
        const float4* x4 = (const float4*)(x + (size_t)row * 8192);
        float4* o4 = (float4*)(out + (size_t)row * 8192);
        for (int tp = tid; tp < 2048; tp += 256) {
            int jj = 2 * tp;
            const float2* s2 = (const float2*)(B + jj);
            float2 q0 = s2[0], q1 = s2[1], q2 = s2[2], q3 = s2[3];
            float e0 = q0.x*c_dlo[1] + q0.y*c_dlo[3] + q1.x*c_dlo[5]
                     + q1.y*c_dlo[7] + q2.x*c_dlo[9] + q2.y*c_dlo[11];
            float od0= q0.x*c_dlo[0] + q0.y*c_dlo[2] + q1.x*c_dlo[4]
                     + q1.y*c_dlo[6] + q2.x*c_dlo[8] + q2.y*c_dlo[10];
            float e1 = q0.y*c_dlo[1] + q1.x*c_dlo[3] + q1.y*c_dlo[5]
                     + q2.x*c_dlo[7] + q2.y*c_dlo[9] + q3.x*c_dlo[11];
            float od1= q0.y*c_dlo[0] + q1.x*c_dlo[2] + q1.y*c_dlo[4]
                     + q2.x*c_dlo[6] + q2.y*c_dlo[8] + q3.x*c_dlo[10];
            float4 xv = x4[tp];
            o4[tp] = make_float4(xv.x + e0, xv.y + od0, xv.z + e1, xv.w + od1);
        }
    }
}

// Dual einsum v12 (verbatim r8, measured 102.8us): k-tile 128 main blocks +
// verbatim-v5 tail blocks. dlo[b,o,k] = sum_i x[b,i,k]*w[i,o,k].
__global__ __launch_bounds__(256)
void einsum_v12(const ushort* __restrict__ xlT, const ushort* __restrict__ xhT,
                const float* __restrict__ w1,   const float* __restrict__ w2,
                float* __restrict__ dlo, float* __restrict__ dh)
{
    __shared__ ushort Xb[2][8192];   // main: [buf][((il*4+g)*128+k)*4+b] 32 KB
    __shared__ float  Wb[2][2048];   // main: [buf][(il*4+j)*128+k]       16 KB

    int bid  = blockIdx.x;
    int lane = threadIdx.x & 63;
    int wv   = threadIdx.x >> 6;
    int t    = threadIdx.x;

    if (bid < 512) {
        // ================= main path: k-width 128 =================
        int kt2 = bid & 3;
        int e   = (bid >> 2) & 1;
        int oq  = bid >> 3;
        const ushort* xT = e ? xhT : xlT;
        const float*  w  = e ? w2  : w1;
        float* outp      = e ? dh  : dlo;
        int o     = oq * 4;
        int kbase = kt2 * 128;

        const ushort* xg0 = xT + (((size_t)wv * 4 + 0) * MODES + kbase) * 4 + lane * 8;
        const ushort* xg1 = xT + (((size_t)wv * 4 + 1) * MODES + kbase) * 4 + lane * 8;
        const ushort* xg2 = xT + (((size_t)wv * 4 + 2) * MODES + kbase) * 4 + lane * 8;
        const ushort* xg3 = xT + (((size_t)wv * 4 + 3) * MODES + kbase) * 4 + lane * 8;
        const size_t XCH = (size_t)4 * 4 * MODES * 4;   // ushorts per chunk (4 i)
        const float* wj0 = w + ((size_t)wv * 256 + o + 0) * MODES + kbase + lane * 2;
        const float* wj1 = w + ((size_t)wv * 256 + o + 1) * MODES + kbase + lane * 2;
        const float* wj2 = w + ((size_t)wv * 256 + o + 2) * MODES + kbase + lane * 2;
        const float* wj3 = w + ((size_t)wv * 256 + o + 3) * MODES + kbase + lane * 2;
        const size_t WCH = (size_t)4 * 256 * MODES;     // floats per chunk

        float acc[4][4][2];
#pragma unroll
        for (int q = 0; q < 4; ++q)
#pragma unroll
            for (int j = 0; j < 4; ++j) { acc[q][j][0] = 0.f; acc[q][j][1] = 0.f; }

        uint4  xv0, xv1, xv2, xv3;
        float2 wv0, wv1, wv2, wv3;

#define LOADCH(CH) do {                                                       \
        size_t xo_ = (size_t)(CH) * XCH;                                      \
        xv0 = *(const uint4*)(xg0 + xo_); xv1 = *(const uint4*)(xg1 + xo_);   \
        xv2 = *(const uint4*)(xg2 + xo_); xv3 = *(const uint4*)(xg3 + xo_);   \
        size_t wo_ = (size_t)(CH) * WCH;                                      \
        wv0 = *(const float2*)(wj0 + wo_); wv1 = *(const float2*)(wj1 + wo_); \
        wv2 = *(const float2*)(wj2 + wo_); wv3 = *(const float2*)(wj3 + wo_); \
    } while (0)

#define WRITECH(NB) do {                                                      \
        *(uint4*)&Xb[NB][(wv * 4 + 0) * 512 + lane * 8] = xv0;                \
        *(uint4*)&Xb[NB][(wv * 4 + 1) * 512 + lane * 8] = xv1;                \
        *(uint4*)&Xb[NB][(wv * 4 + 2) * 512 + lane * 8] = xv2;                \
        *(uint4*)&Xb[NB][(wv * 4 + 3) * 512 + lane * 8] = xv3;                \
        *(float2*)&Wb[NB][(wv * 4 + 0) * 128 + lane * 2] = wv0;               \
        *(float2*)&Wb[NB][(wv * 4 + 1) * 128 + lane * 2] = wv1;               \
        *(float2*)&Wb[NB][(wv * 4 + 2) * 128 + lane * 2] = wv2;               \
        *(float2*)&Wb[NB][(wv * 4 + 3) * 128 + lane * 2] = wv3;               \
    } while (0)

        LOADCH(0);
        WRITECH(0);
        __syncthreads();

        for (int ch = 0; ch < 64; ++ch) {
            int cur = ch & 1, nb = cur ^ 1;
            if (ch < 63) LOADCH(ch + 1);

#pragma unroll
            for (int ii = 0; ii < 4; ++ii) {
                uint4 xq = *(const uint4*)&Xb[cur][((ii * 4 + wv) * 128 + 2 * lane) * 4];
                float x00 = __uint_as_float(xq.x << 16);
                float x01 = __uint_as_float(xq.x & 0xffff0000u);
                float x02 = __uint_as_float(xq.y << 16);
                float x03 = __uint_as_float(xq.y & 0xffff0000u);
                float x10 = __uint_as_float(xq.z << 16);
                float x11 = __uint_as_float(xq.z & 0xffff0000u);
                float x12 = __uint_as_float(xq.w << 16);
                float x13 = __uint_as_float(xq.w & 0xffff0000u);
                float2 wq0 = *(const float2*)&Wb[cur][(ii * 4 + 0) * 128 + 2 * lane];
                float2 wq1 = *(const float2*)&Wb[cur][(ii * 4 + 1) * 128 + 2 * lane];
                float2 wq2 = *(const float2*)&Wb[cur][(ii * 4 + 2) * 128 + 2 * lane];
                float2 wq3 = *(const float2*)&Wb[cur][(ii * 4 + 3) * 128 + 2 * lane];
                acc[0][0][0] += x00 * wq0.x; acc[0][0][1] += x10 * wq0.y;
                acc[0][1][0] += x00 * wq1.x; acc[0][1][1] += x10 * wq1.y;
                acc[0][2][0] += x00 * wq2.x; acc[0][2][1] += x10 * wq2.y;
                acc[0][3][0] += x00 * wq3.x; acc[0][3][1] += x10 * wq3.y;
                acc[1][0][0] += x01 * wq0.x; acc[1][0][1] += x11 * wq0.y;
                acc[1][1][0] += x01 * wq1.x; acc[1][1][1] += x11 * wq1.y;
                acc[1][2][0] += x01 * wq2.x; acc[1][2][1] += x11 * wq2.y;
                acc[1][3][0] += x01 * wq3.x; acc[1][3][1] += x11 * wq3.y;
                acc[2][0][0] += x02 * wq0.x; acc[2][0][1] += x12 * wq0.y;
                acc[2][1][0] += x02 * wq1.x; acc[2][1][1] += x12 * wq1.y;
                acc[2][2][0] += x02 * wq2.x; acc[2][2][1] += x12 * wq2.y;
                acc[2][3][0] += x02 * wq3.x; acc[2][3][1] += x12 * wq3.y;
                acc[3][0][0] += x03 * wq0.x; acc[3][0][1] += x13 * wq0.y;
                acc[3][1][0] += x03 * wq1.x; acc[3][1][1] += x13 * wq1.y;
                acc[3][2][0] += x03 * wq2.x; acc[3][2][1] += x13 * wq2.y;
                acc[3][3][0] += x03 * wq3.x; acc[3][3][1] += x13 * wq3.y;
            }

            if (ch < 63) WRITECH(nb);
            __syncthreads();
        }
#undef LOADCH
#undef WRITECH

#pragma unroll
        for (int q = 0; q < 4; ++q) {
            int b = 4 * wv + q;
#pragma unroll
            for (int j = 0; j < 4; ++j)
                *(float2*)&outp[((size_t)b * 256 + o + j) * MODES + kbase + 2 * lane]
                    = make_float2(acc[q][j][0], acc[q][j][1]);
        }
    } else {
        // ================= tail path: verbatim v5, kbase=458 =================
        int tb = bid - 512;
        int e  = tb >> 6;
        int oq = tb & 63;
        const ushort* xT = e ? xhT : xlT;
        const float*  w  = e ? w2  : w1;
        float* outp      = e ? dh  : dlo;
        int kbase = MODES - 64;   // 458
        int o     = oq * 4;

        int run = t >> 4, piece = t & 15;
        int il = run >> 2, sub = run & 3;

        const ushort* xrunb = xT + (((size_t)il * 4 + sub) * MODES + kbase) * 4 + piece * 16;
        const size_t xistr = (size_t)4 * MODES * 4;
        const float* wrunb = w + ((size_t)il * 256 + o + sub) * MODES + kbase + piece * 4;
        const size_t wistr = (size_t)256 * MODES;

        float acc[4][4];
#pragma unroll
        for (int q = 0; q < 4; ++q)
#pragma unroll
            for (int j = 0; j < 4; ++j) acc[q][j] = 0.f;

        {
            uint4 v0 = *(const uint4*)(xrunb);
            uint4 v1 = *(const uint4*)(xrunb + 8);
            float f0 = wrunb[0], f1 = wrunb[1], f2 = wrunb[2], f3 = wrunb[3];
            uint4* xd = (uint4*)&Xb[0][t * 16];
            xd[0] = v0; xd[1] = v1;
            float4* wd = (float4*)&Wb[0][t * 4];
            *wd = make_float4(f0, f1, f2, f3);
        }
        __syncthreads();

        for (int ch = 0; ch < 64; ++ch) {
            int cur = ch & 1, nb = cur ^ 1;
            uint4 v0, v1; float f0, f1, f2, f3;
            if (ch < 63) {
                const ushort* xs = xrunb + (size_t)(ch + 1) * 4 * xistr;
                v0 = *(const uint4*)(xs);
                v1 = *(const uint4*)(xs + 8);
                const float* wsv = wrunb + (size_t)(ch + 1) * 4 * wistr;
                f0 = wsv[0]; f1 = wsv[1]; f2 = wsv[2]; f3 = wsv[3];
            }

#pragma unroll
            for (int ii = 0; ii < 4; ++ii) {
                uint2 xp = *(const uint2*)&Xb[cur][(((ii * 4) + wv) * 64 + lane) * 4];
                float x0 = __uint_as_float(xp.x << 16);
                float x1 = __uint_as_float(xp.x & 0xffff0000u);
                float x2 = __uint_as_float(xp.y << 16);
                float x3 = __uint_as_float(xp.y & 0xffff0000u);
                float wr0 = Wb[cur][(ii * 4 + 0) * 64 + lane];
                float wr1 = Wb[cur][(ii * 4 + 1) * 64 + lane];
                float wr2 = Wb[cur][(ii * 4 + 2) * 64 + lane];
                float wr3 = Wb[cur][(ii * 4 + 3) * 64 + lane];
                acc[0][0] += x0 * wr0; acc[0][1] += x0 * wr1;
                acc[0][2] += x0 * wr2; acc[0][3] += x0 * wr3;
                acc[1][0] += x1 * wr0; acc[1][1] += x1 * wr1;
                acc[1][2] += x1 * wr2; acc[1][3] += x1 * wr3;
                acc[2][0] += x2 * wr0; acc[2][1] += x2 * wr1;
                acc[2][2] += x2 * wr2; acc[2][3] += x2 * wr3;
                acc[3][0] += x3 * wr0; acc[3][1] += x3 * wr1;
                acc[3][2] += x3 * wr2; acc[3][3] += x3 * wr3;
            }

            if (ch < 63) {
                uint4* xd = (uint4*)&Xb[nb][t * 16];
                xd[0] = v0; xd[1] = v1;
                float4* wd = (float4*)&Wb[nb][t * 4];
                *wd = make_float4(f0, f1, f2, f3);
            }
            __syncthreads();
        }

#pragma unroll
        for (int q = 0; q < 4; ++q) {
            int b = 4 * wv + q;
#pragma unroll
            for (int j = 0; j < 4; ++j)
                outp[((size_t)b * 256 + o + j) * MODES + kbase + lane] = acc[q][j];
        }
    }
}

extern "C" void kernel_launch(void* const* d_in, const int* in_sizes, int n_in,
                              void* d_out, int out_size, void* d_ws, size_t ws_size,
                              hipStream_t stream)
{
    const float* x  = (const float*)d_in[0];
    const float* w1 = (const float*)d_in[1];
    const float* w2 = (const float*)d_in[2];
    float* out = (float*)d_out;
    float* ws  = (float*)d_ws;

    const size_t SZ = (size_t)NROWS * M4;   // 2,138,112
    float* lo4 = ws;
    float* h4  = lo4 + SZ;
    float* dlo = h4  + SZ;
    float* dh  = dlo + SZ;
    ushort* xlT = (ushort*)(dh + SZ);        // SZ ushorts
    ushort* xhT = xlT + SZ;                  // SZ ushorts

    dim3 blk(256);

    dwt_fused3<<<NROWS, blk, 0, stream>>>(x, lo4, h4, xlT, xhT);
    einsum_v12<<<640, blk, 0, stream>>>(xlT, xhT, w1, w2, dlo, dh);
    idwt_delta3<<<NROWS, blk, 0, stream>>>(dlo, dh, lo4, h4, x, out);
}